// Round 8
// baseline (50.295 us; speedup 1.0000x reference)
//
#include <hip/hip_runtime.h>
#include <math.h>

#define HH 128   // hidden size
#define SS 1000  // sequence length
#define NT 1024  // threads per block (16 waves)
#define NW (NT / 64)

#define C1 2.8853900817779268f  // 2*log2(e)
#define C2 1.4426950408889634f  // log2(e)

typedef float v2f __attribute__((ext_vector_type(2)));

// DPP add helpers. row_shr:N sums within 16-lane rows; row_bcast15 (0x142)
// pushes each row's lane15 into the next row (completes 32-lane group sums
// at lanes 31 and 63).
template <int CTRL>
__device__ __forceinline__ float dpp_add(float x) {
    int s = __builtin_amdgcn_update_dpp(0, __builtin_bit_cast(int, x),
                                        CTRL, 0xF, 0xF, true);
    return x + __builtin_bit_cast(float, s);
}

__global__ __launch_bounds__(NT) void sc_fused(
    const float* __restrict__ stat, const float* __restrict__ dyn,
    const float* __restrict__ enc_s_w, const float* __restrict__ enc_s_b,
    const float* __restrict__ enc_d_w, const float* __restrict__ enc_d_b,
    const float* __restrict__ v, const float* __restrict__ W,
    const float* __restrict__ dense_w, const float* __restrict__ dense_b,
    const float* __restrict__ lin_w, const float* __restrict__ lin_b,
    float* __restrict__ out) {
    const int b    = blockIdx.x;
    const int t    = threadIdx.x;
    const int wave = t >> 6;
    const int lane = t & 63;
    const int g    = t & 31;   // h-slice: h = 4g .. 4g+3
    const int sg   = t >> 5;   // s-group 0..31; s = pass*32 + sg

    __shared__ __align__(16) float4 xs[NT];    // {x0,x1,yv,0} per s (16 KB)
    __shared__ __align__(16) float kc[8][HH];  // folded constants (4 KB)
    __shared__ float4 red4[2][NW];
    __shared__ float hy_sh[HH];
    __shared__ float svc2_sh;

    // ---- phase 0: stage per-s inputs (coalesced) ----
    {
        float x0 = 0.f, x1 = 0.f, yv = 0.f;
        if (t < SS) {
            const float* sb = stat + (size_t)b * 2 * SS;
            x0 = sb[t];
            x1 = sb[SS + t];
            yv = dyn[(size_t)b * 2 * SS + SS + t];
        }
        xs[t] = make_float4(x0, x1, yv, 0.f);
    }

    // ---- phase 1: constant folding, split-k over 8 lanes, DPP reduce ----
    {
        const int fh = t >> 3;   // h = 0..127
        const int fq = t & 7;    // k-eighth
        const float4* W1 = (const float4*)(W + fh * (3 * HH));
        const float4* W2 = (const float4*)(W + fh * (3 * HH) + HH);
        const float4* W3 = (const float4*)(W + fh * (3 * HH) + 2 * HH);
        const float4* ES = (const float4*)enc_s_w;
        const float4* ED = (const float4*)enc_d_w;
        const float4* SB = (const float4*)enc_s_b;
        const float4* DB = (const float4*)enc_d_b;
        float a0 = 0.f, a1 = 0.f, ad = 0.f, cc = 0.f, w30 = 0.f, w31 = 0.f, w3b = 0.f;
        #pragma unroll
        for (int j = 0; j < 4; ++j) {
            const int k4 = fq * 4 + j;
            float4 w1 = W1[k4], w2 = W2[k4], w3 = W3[k4];
            float4 e01 = ES[2 * k4], e23 = ES[2 * k4 + 1];
            float4 d01 = ED[2 * k4], d23 = ED[2 * k4 + 1];
            float4 sb = SB[k4], db = DB[k4];
            a0 = fmaf(w1.x, e01.x, a0); a0 = fmaf(w1.y, e01.z, a0);
            a0 = fmaf(w1.z, e23.x, a0); a0 = fmaf(w1.w, e23.z, a0);
            a1 = fmaf(w1.x, e01.y, a1); a1 = fmaf(w1.y, e01.w, a1);
            a1 = fmaf(w1.z, e23.y, a1); a1 = fmaf(w1.w, e23.w, a1);
            ad = fmaf(w2.x, d01.x + d01.y, ad); ad = fmaf(w2.y, d01.z + d01.w, ad);
            ad = fmaf(w2.z, d23.x + d23.y, ad); ad = fmaf(w2.w, d23.z + d23.w, ad);
            cc = fmaf(w1.x, sb.x, cc); cc = fmaf(w1.y, sb.y, cc);
            cc = fmaf(w1.z, sb.z, cc); cc = fmaf(w1.w, sb.w, cc);
            cc = fmaf(w2.x, db.x, cc); cc = fmaf(w2.y, db.y, cc);
            cc = fmaf(w2.z, db.z, cc); cc = fmaf(w2.w, db.w, cc);
            w30 = fmaf(w3.x, e01.x, w30); w30 = fmaf(w3.y, e01.z, w30);
            w30 = fmaf(w3.z, e23.x, w30); w30 = fmaf(w3.w, e23.z, w30);
            w31 = fmaf(w3.x, e01.y, w31); w31 = fmaf(w3.y, e01.w, w31);
            w31 = fmaf(w3.z, e23.y, w31); w31 = fmaf(w3.w, e23.w, w31);
            w3b = fmaf(w3.x, sb.x, w3b); w3b = fmaf(w3.y, sb.y, w3b);
            w3b = fmaf(w3.z, sb.z, w3b); w3b = fmaf(w3.w, sb.w, w3b);
        }
        // 8-lane suffix reduce: lane fq==7 of each group holds the total
        a0  = dpp_add<0x111>(a0);  a0  = dpp_add<0x112>(a0);  a0  = dpp_add<0x114>(a0);
        a1  = dpp_add<0x111>(a1);  a1  = dpp_add<0x112>(a1);  a1  = dpp_add<0x114>(a1);
        ad  = dpp_add<0x111>(ad);  ad  = dpp_add<0x112>(ad);  ad  = dpp_add<0x114>(ad);
        cc  = dpp_add<0x111>(cc);  cc  = dpp_add<0x112>(cc);  cc  = dpp_add<0x114>(cc);
        w30 = dpp_add<0x111>(w30); w30 = dpp_add<0x112>(w30); w30 = dpp_add<0x114>(w30);
        w31 = dpp_add<0x111>(w31); w31 = dpp_add<0x112>(w31); w31 = dpp_add<0x114>(w31);
        w3b = dpp_add<0x111>(w3b); w3b = dpp_add<0x112>(w3b); w3b = dpp_add<0x114>(w3b);
        if (fq == 7) {
            kc[0][fh] = a0 * C1;
            kc[1][fh] = a1 * C1;
            kc[2][fh] = ad * C1;
            kc[4][fh] = cc * C1;
            kc[5][fh] = (cc + w3b) * C1;
            kc[6][fh] = w30 * C1;
            kc[7][fh] = w31 * C1;
        }
        if (t < HH) kc[3][t] = v[t];
        if (t < 32) {  // sum(v) via wave-0 lanes 0..31
            float4 x = ((const float4*)v)[t];
            float s = (x.x + x.y) + (x.z + x.w);
            #pragma unroll
            for (int off = 1; off < 32; off <<= 1) s += __shfl_xor(s, off);
            if (t == 0) svc2_sh = s * C2;
        }
    }
    __syncthreads();

    // ---- phase 2: 16 resident constant floats (fits easily in 64 VGPR) ----
    const int h4 = g * 4;
    float4 u;
    u = *(const float4*)&kc[0][h4]; const v2f a0_0 = {u.x, u.y}, a0_1 = {u.z, u.w};
    u = *(const float4*)&kc[1][h4]; const v2f a1_0 = {u.x, u.y}, a1_1 = {u.z, u.w};
    u = *(const float4*)&kc[2][h4]; const v2f ad_0 = {u.x, u.y}, ad_1 = {u.z, u.w};
    u = *(const float4*)&kc[3][h4]; const v2f vv_0 = {u.x, u.y}, vv_1 = {u.z, u.w};
    const float svc2 = svc2_sh;
    const v2f one2 = {1.f, 1.f};
    const bool owner = (g == 31);

    float X0 = 0.f, X1 = 0.f;

    for (int iter = 0; iter < 3; ++iter) {
        v2f cg_0, cg_1;
        if (iter == 0) {
            u = *(const float4*)&kc[4][h4];
            cg_0 = (v2f){u.x, u.y};
            cg_1 = (v2f){u.z, u.w};
        } else {
            float4 ub = *(const float4*)&kc[5][h4];
            float4 u0 = *(const float4*)&kc[6][h4];
            float4 u1 = *(const float4*)&kc[7][h4];
            v2f X0v = {X0, X0}, X1v = {X1, X1};
            cg_0 = __builtin_elementwise_fma(
                (v2f){u0.x, u0.y}, X0v,
                __builtin_elementwise_fma((v2f){u1.x, u1.y}, X1v, (v2f){ub.x, ub.y}));
            cg_1 = __builtin_elementwise_fma(
                (v2f){u0.z, u0.w}, X0v,
                __builtin_elementwise_fma((v2f){u1.z, u1.w}, X1v, (v2f){ub.z, ub.w}));
        }

        float S = 0.f, Sx0 = 0.f, Sx1 = 0.f;
        #pragma unroll 2
        for (int pass = 0; pass < 32; ++pass) {
            const int s = pass * 32 + sg;
            float4 x = xs[s];
            v2f vx0 = {x.x, x.x}, vx1 = {x.y, x.y}, vyv = {x.z, x.z};
            v2f z0 = __builtin_elementwise_fma(
                a0_0, vx0, __builtin_elementwise_fma(
                    a1_0, vx1, __builtin_elementwise_fma(ad_0, vyv, cg_0)));
            v2f z1 = __builtin_elementwise_fma(
                a0_1, vx0, __builtin_elementwise_fma(
                    a1_1, vx1, __builtin_elementwise_fma(ad_1, vyv, cg_1)));
            v2f e0, e1;
            e0.x = __builtin_amdgcn_exp2f(z0.x);
            e0.y = __builtin_amdgcn_exp2f(z0.y);
            e1.x = __builtin_amdgcn_exp2f(z1.x);
            e1.y = __builtin_amdgcn_exp2f(z1.y);
            v2f d0 = e0 + one2, d1 = e1 + one2;
            v2f r0, r1;
            r0.x = __builtin_amdgcn_rcpf(d0.x);
            r0.y = __builtin_amdgcn_rcpf(d0.y);
            r1.x = __builtin_amdgcn_rcpf(d1.x);
            r1.y = __builtin_amdgcn_rcpf(d1.y);
            v2f acc2 = __builtin_elementwise_fma(vv_0, r0, (v2f){0.f, 0.f});
            acc2 = __builtin_elementwise_fma(vv_1, r1, acc2);
            float acc = acc2.x + acc2.y;
            // 32-lane group sum -> lanes 31 and 63
            acc = dpp_add<0x111>(acc);  // row_shr:1
            acc = dpp_add<0x112>(acc);  // row_shr:2
            acc = dpp_add<0x114>(acc);  // row_shr:4
            acc = dpp_add<0x118>(acc);  // row_shr:8
            acc = dpp_add<0x142>(acc);  // row_bcast15
            const bool own = owner && (s < SS);
            float arg = own ? fmaf(-C1, acc, svc2) : -200.f;  // exp2(-200) == +0
            float p = __builtin_amdgcn_exp2f(arg);
            S   += p;
            Sx0  = fmaf(p, x.x, Sx0);
            Sx1  = fmaf(p, x.y, Sx1);
        }
        // owners at lanes 31, 63 -> lane 31 holds wave total
        S   += __shfl_xor(S, 32);
        Sx0 += __shfl_xor(Sx0, 32);
        Sx1 += __shfl_xor(Sx1, 32);
        if (lane == 31) red4[iter & 1][wave] = make_float4(S, Sx0, Sx1, 0.f);
        __syncthreads();  // only barrier per iteration
        float4 w4 = red4[iter & 1][lane & 15];
        #pragma unroll
        for (int off = 1; off < 16; off <<= 1) {
            w4.x += __shfl_xor(w4.x, off);
            w4.y += __shfl_xor(w4.y, off);
            w4.z += __shfl_xor(w4.z, off);
        }
        float inv = __builtin_amdgcn_rcpf(w4.x);
        X0 = w4.y * inv;  // uniform across block
        X1 = w4.z * inv;
    }

    // hy[h] = enc_s_w[h,0]*X0 + enc_s_w[h,1]*X1 + enc_s_b[h]
    if (t < HH)
        hy_sh[t] = fmaf(enc_s_w[2 * t], X0, fmaf(enc_s_w[2 * t + 1], X1, enc_s_b[t]));
    __syncthreads();

    // out[b] = lin_w @ relu(dense_w @ hy + dense_b) + lin_b
    float o = 0.f;
    if (t < HH) {
        const float4* dw4 = (const float4*)(dense_w + t * HH);
        const float4* hy4 = (const float4*)hy_sh;
        float r = dense_b[t];
        #pragma unroll 4
        for (int k = 0; k < HH / 4; ++k) {
            float4 d4 = dw4[k], h4v = hy4[k];
            r = fmaf(d4.x, h4v.x, fmaf(d4.y, h4v.y, fmaf(d4.z, h4v.z, fmaf(d4.w, h4v.w, r))));
        }
        o = lin_w[t] * fmaxf(r, 0.f);
    }
    #pragma unroll
    for (int off = 32; off > 0; off >>= 1) o += __shfl_xor(o, off);
    if (lane == 0) red4[0][wave].x = o;
    __syncthreads();
    if (t == 0) {
        float s = 0.f;
        for (int i = 0; i < NW; ++i) s += red4[0][i].x;
        out[b] = s + lin_b[0];
    }
}

extern "C" void kernel_launch(void* const* d_in, const int* in_sizes, int n_in,
                              void* d_out, int out_size, void* d_ws, size_t ws_size,
                              hipStream_t stream) {
    const float* stat    = (const float*)d_in[0];
    const float* dyn     = (const float*)d_in[1];
    const float* enc_s_w = (const float*)d_in[2];
    const float* enc_s_b = (const float*)d_in[3];
    const float* enc_d_w = (const float*)d_in[4];
    const float* enc_d_b = (const float*)d_in[5];
    const float* v       = (const float*)d_in[6];
    const float* W       = (const float*)d_in[7];
    const float* dense_w = (const float*)d_in[8];
    const float* dense_b = (const float*)d_in[9];
    const float* lin_w   = (const float*)d_in[10];
    const float* lin_b   = (const float*)d_in[11];
    float* out = (float*)d_out;

    const int B = in_sizes[0] / (2 * SS);

    hipLaunchKernelGGL(sc_fused, dim3(B), dim3(NT), 0, stream,
                       stat, dyn, enc_s_w, enc_s_b, enc_d_w, enc_d_b, v, W,
                       dense_w, dense_b, lin_w, lin_b, out);
}